// Round 1
// baseline (515.403 us; speedup 1.0000x reference)
//
#include <hip/hip_runtime.h>
#include <math.h>

#define Hd 128
#define Wd 128
#define HW 16384      // 128*128
#define EPSc 1e-6f

// ---------------------------------------------------------------------------
// K1: depthwise 3x3 sobel -> gx, gy, mag, dir
// grid (8,8,B*64=128), block (16,16)
__global__ void k_sobel(const float* __restrict__ x,
                        const float* __restrict__ wgx,
                        const float* __restrict__ wgy,
                        float* __restrict__ gx, float* __restrict__ gy,
                        float* __restrict__ mag, float* __restrict__ dir) {
    int tx = threadIdx.x, ty = threadIdx.y;
    int xw = blockIdx.x * 16 + tx;
    int yh = blockIdx.y * 16 + ty;
    int bc = blockIdx.z;            // b*64 + c
    int c  = bc & 63;
    const float* xp = x + (size_t)bc * HW;
    float wx[9], wy[9];
#pragma unroll
    for (int i = 0; i < 9; i++) { wx[i] = wgx[c * 9 + i]; wy[i] = wgy[c * 9 + i]; }
    float sx = 0.f, sy = 0.f;
#pragma unroll
    for (int dy = -1; dy <= 1; dy++) {
        int yy = yh + dy;
#pragma unroll
        for (int dx = -1; dx <= 1; dx++) {
            int xx = xw + dx;
            float v = (yy >= 0 && yy < Hd && xx >= 0 && xx < Wd) ? xp[yy * Wd + xx] : 0.f;
            int t = (dy + 1) * 3 + (dx + 1);
            sx += wx[t] * v;
            sy += wy[t] * v;
        }
    }
    int o = bc * HW + yh * Wd + xw;
    gx[o] = sx;
    gy[o] = sy;
    mag[o] = sqrtf(sx * sx + sy * sy + EPSc);
    dir[o] = atan2f(sy, sx);
}

// ---------------------------------------------------------------------------
// K2: 1x1 conv [64 out][128 in] + relu.  gf = concat(gx, gy) on channel dim.
// one thread per pixel, all 64 outputs. grid 512 x block 64
__global__ void k_ga1(const float* __restrict__ gx, const float* __restrict__ gy,
                      const float* __restrict__ w1, const float* __restrict__ b1,
                      float* __restrict__ ga1) {
    int p = blockIdx.x * 64 + threadIdx.x;   // 0..32767
    int b = p >> 14;
    int s = p & (HW - 1);
    const float* gxp = gx + (size_t)b * 64 * HW + s;
    const float* gyp = gy + (size_t)b * 64 * HW + s;
    float acc[64];
#pragma unroll
    for (int co = 0; co < 64; co++) acc[co] = b1[co];
    for (int ci = 0; ci < 64; ci++) {
        float vx = gxp[ci * HW];
        float vy = gyp[ci * HW];
#pragma unroll
        for (int co = 0; co < 64; co++)
            acc[co] += vx * w1[co * 128 + ci] + vy * w1[co * 128 + 64 + ci];
    }
    float* op = ga1 + (size_t)b * 64 * HW + s;
#pragma unroll
    for (int co = 0; co < 64; co++) op[co * HW] = fmaxf(acc[co], 0.f);
}

// ---------------------------------------------------------------------------
// K2b: 1x1 conv [16 out][64 in] + relu. grid 512 x block 64
__global__ void k_ga2(const float* __restrict__ ga1, const float* __restrict__ w2,
                      const float* __restrict__ b2, float* __restrict__ ga2) {
    int p = blockIdx.x * 64 + threadIdx.x;
    int b = p >> 14;
    int s = p & (HW - 1);
    const float* ip = ga1 + (size_t)b * 64 * HW + s;
    float acc[16];
#pragma unroll
    for (int co = 0; co < 16; co++) acc[co] = b2[co];
    for (int ci = 0; ci < 64; ci++) {
        float v = ip[ci * HW];
#pragma unroll
        for (int co = 0; co < 16; co++) acc[co] += v * w2[co * 64 + ci];
    }
    float* op = ga2 + (size_t)b * 16 * HW + s;
#pragma unroll
    for (int co = 0; co < 16; co++) op[co * HW] = fmaxf(acc[co], 0.f);
}

// ---------------------------------------------------------------------------
// K3: 5x5 windowed weighted circular-variance -> per-channel consistency
// grid (8,8,128), block (16,16)
__global__ void k_cons(const float* __restrict__ mag, const float* __restrict__ dir,
                       float* __restrict__ cons) {
    int tx = threadIdx.x, ty = threadIdx.y;
    int xw = blockIdx.x * 16 + tx;
    int yh = blockIdx.y * 16 + ty;
    int bc = blockIdx.z;
    const float* mp = mag + (size_t)bc * HW;
    const float* dp = dir + (size_t)bc * HW;
    float m[25], d[25];
#pragma unroll
    for (int dy = -2; dy <= 2; dy++) {
        int yy = yh + dy;
#pragma unroll
        for (int dx = -2; dx <= 2; dx++) {
            int xx = xw + dx;
            int t = (dy + 2) * 5 + (dx + 2);
            bool ok = (yy >= 0 && yy < Hd && xx >= 0 && xx < Wd);
            m[t] = ok ? mp[yy * Wd + xx] : 0.f;
            d[t] = ok ? dp[yy * Wd + xx] : 0.f;
        }
    }
    float sm = 0.f, sdm = 0.f;
#pragma unroll
    for (int t = 0; t < 25; t++) { sm += m[t]; sdm += d[t] * m[t]; }
    float wmean = sdm / (sm + EPSc);
    float sv = 0.f;
#pragma unroll
    for (int t = 0; t < 25; t++) { float dd = d[t] - wmean; sv += dd * dd * m[t]; }
    float wstd = sqrtf(sv / (sm + EPSc));
    cons[bc * HW + yh * Wd + xw] = 1.f - tanhf(wstd);
}

// ---------------------------------------------------------------------------
// K4: mean over 64 channels. grid 128 x block 256
__global__ void k_consmean(const float* __restrict__ cons, float* __restrict__ cm) {
    int p = blockIdx.x * 256 + threadIdx.x;  // 0..32767
    int b = p >> 14;
    int s = p & (HW - 1);
    const float* cp = cons + (size_t)b * 64 * HW + s;
    float acc = 0.f;
#pragma unroll
    for (int c = 0; c < 64; c++) acc += cp[c * HW];
    cm[p] = acc * (1.f / 64.f);
}

// ---------------------------------------------------------------------------
// K5: 3x3 conv [16][16] + relu on ga2. grid (8,8,2), block (16,16)
__global__ void k_cd1(const float* __restrict__ ga2, const float* __restrict__ w,
                      const float* __restrict__ bias, float* __restrict__ ew1) {
    int tx = threadIdx.x, ty = threadIdx.y;
    int xw = blockIdx.x * 16 + tx;
    int yh = blockIdx.y * 16 + ty;
    int b = blockIdx.z;
    const float* ip = ga2 + (size_t)b * 16 * HW;
    float acc[16];
#pragma unroll
    for (int co = 0; co < 16; co++) acc[co] = bias[co];
    for (int ci = 0; ci < 16; ci++) {
#pragma unroll
        for (int dy = -1; dy <= 1; dy++) {
            int yy = yh + dy;
#pragma unroll
            for (int dx = -1; dx <= 1; dx++) {
                int xx = xw + dx;
                float v = (yy >= 0 && yy < Hd && xx >= 0 && xx < Wd)
                              ? ip[ci * HW + yy * Wd + xx] : 0.f;
                int t = (dy + 1) * 3 + (dx + 1);
#pragma unroll
                for (int co = 0; co < 16; co++) acc[co] += v * w[co * 144 + ci * 9 + t];
            }
        }
    }
    float* op = ew1 + (size_t)b * 16 * HW + yh * Wd + xw;
#pragma unroll
    for (int co = 0; co < 16; co++) op[co * HW] = fmaxf(acc[co], 0.f);
}

// ---------------------------------------------------------------------------
// K6: 1x1 conv [1][16] + sigmoid, * cons_mean. grid 128 x block 256
__global__ void k_ew(const float* __restrict__ ew1, const float* __restrict__ w,
                     const float* __restrict__ bias, const float* __restrict__ cm,
                     float* __restrict__ ew) {
    int p = blockIdx.x * 256 + threadIdx.x;
    int b = p >> 14;
    int s = p & (HW - 1);
    const float* ip = ew1 + (size_t)b * 16 * HW + s;
    float acc = bias[0];
#pragma unroll
    for (int ci = 0; ci < 16; ci++) acc += ip[ci * HW] * w[ci];
    float sig = 1.f / (1.f + expf(-acc));
    ew[p] = sig * cm[p];
}

// ---------------------------------------------------------------------------
// K7/K8: 3x3 conv [64][64], LDS-tiled. 16x16 spatial tile, 16 out-channels
// per block -> grid (8,8,B*4=8), block 256. FINAL=0: relu; FINAL=1: epilogue
// out = x + alpha*ew*conv.
template <int FINAL>
__global__ __launch_bounds__(256, 2)
void k_conv64(const float* __restrict__ in, const float* __restrict__ w,
              const float* __restrict__ bias, float* __restrict__ out,
              const float* __restrict__ x, const float* __restrict__ ew,
              const float* __restrict__ alpha_p) {
    __shared__ float lds[16][18 * 18];   // 20.7 KB: 16 in-channels of 18x18 halo tile
    int tid = threadIdx.x;
    int tx = tid & 15, ty = tid >> 4;
    int x0 = blockIdx.x * 16, y0 = blockIdx.y * 16;
    int b = blockIdx.z >> 2;
    int co_base = (blockIdx.z & 3) * 16;
    const float* ip = in + (size_t)b * 64 * HW;
    float acc[16];
#pragma unroll
    for (int co = 0; co < 16; co++) acc[co] = bias[co_base + co];

    for (int cc = 0; cc < 4; cc++) {     // 4 chunks of 16 input channels
        __syncthreads();
        for (int i = tid; i < 16 * 324; i += 256) {
            int ci = i / 324;
            int r = i - ci * 324;
            int yy = r / 18;
            int xx = r - yy * 18;
            int gyy = y0 - 1 + yy, gxx = x0 - 1 + xx;
            float v = (gyy >= 0 && gyy < Hd && gxx >= 0 && gxx < Wd)
                          ? ip[(cc * 16 + ci) * HW + gyy * Wd + gxx] : 0.f;
            lds[ci][yy * 18 + xx] = v;
        }
        __syncthreads();
        for (int ci = 0; ci < 16; ci++) {
            int wbase = (cc * 16 + ci) * 9;
#pragma unroll
            for (int dy = 0; dy < 3; dy++) {
#pragma unroll
                for (int dx = 0; dx < 3; dx++) {
                    float v = lds[ci][(ty + dy) * 18 + tx + dx];
                    int wi = wbase + dy * 3 + dx;
#pragma unroll
                    for (int co = 0; co < 16; co++)
                        acc[co] += v * w[(co_base + co) * 576 + wi];
                }
            }
        }
    }
    int sp = (y0 + ty) * Wd + (x0 + tx);
    if (FINAL) {
        float ae = alpha_p[0] * ew[b * HW + sp];
#pragma unroll
        for (int co = 0; co < 16; co++) {
            size_t o = (size_t)(b * 64 + co_base + co) * HW + sp;
            out[o] = x[o] + ae * acc[co];
        }
    } else {
#pragma unroll
        for (int co = 0; co < 16; co++)
            out[(size_t)(b * 64 + co_base + co) * HW + sp] = fmaxf(acc[co], 0.f);
    }
}

// ---------------------------------------------------------------------------
extern "C" void kernel_launch(void* const* d_in, const int* in_sizes, int n_in,
                              void* d_out, int out_size, void* d_ws, size_t ws_size,
                              hipStream_t stream) {
    const float* x     = (const float*)d_in[0];
    const float* wgx   = (const float*)d_in[1];
    const float* wgy   = (const float*)d_in[2];
    const float* ga_w1 = (const float*)d_in[3];
    const float* ga_b1 = (const float*)d_in[4];
    const float* ga_w2 = (const float*)d_in[5];
    const float* ga_b2 = (const float*)d_in[6];
    const float* cd_w1 = (const float*)d_in[7];
    const float* cd_b1 = (const float*)d_in[8];
    const float* cd_w2 = (const float*)d_in[9];
    const float* cd_b2 = (const float*)d_in[10];
    const float* ec_w1 = (const float*)d_in[11];
    const float* ec_b1 = (const float*)d_in[12];
    const float* ec_w2 = (const float*)d_in[13];
    const float* ec_b2 = (const float*)d_in[14];
    const float* alpha = (const float*)d_in[15];
    float* out = (float*)d_out;
    float* ws  = (float*)d_ws;

    const int N = 2 * 64 * HW;   // 2,097,152

    // buffer plan (aliased by liveness):
    float* gx   = ws + 0 * (size_t)N;   // K1 out; dead after K2  -> reused as cons (K3)
    float* gy   = ws + 1 * (size_t)N;   // K1 out; dead after K2
    float* mag  = ws + 2 * (size_t)N;   // K1 out; dead after K3  -> reused as ee1 (K7)
    float* dirb = ws + 3 * (size_t)N;   // K1 out; dead after K3
    float* ga1  = ws + 4 * (size_t)N;   // K2 out; dead after K2b
    float* ga2  = ws + 5 * (size_t)N;            // 2*16*HW = 524288
    float* ew1  = ga2 + 2 * 16 * HW;             // 524288
    float* cm   = ew1 + 2 * 16 * HW;             // 32768
    float* ew   = cm + 2 * HW;                   // 32768
    float* cons = gx;
    float* ee1  = mag;

    dim3 b16(16, 16);
    k_sobel<<<dim3(8, 8, 128), b16, 0, stream>>>(x, wgx, wgy, gx, gy, mag, dirb);
    k_ga1<<<512, 64, 0, stream>>>(gx, gy, ga_w1, ga_b1, ga1);
    k_ga2<<<512, 64, 0, stream>>>(ga1, ga_w2, ga_b2, ga2);
    k_cons<<<dim3(8, 8, 128), b16, 0, stream>>>(mag, dirb, cons);
    k_consmean<<<128, 256, 0, stream>>>(cons, cm);
    k_cd1<<<dim3(8, 8, 2), b16, 0, stream>>>(ga2, cd_w1, cd_b1, ew1);
    k_ew<<<128, 256, 0, stream>>>(ew1, cd_w2, cd_b2, cm, ew);
    k_conv64<0><<<dim3(8, 8, 8), 256, 0, stream>>>(x, ec_w1, ec_b1, ee1,
                                                   nullptr, nullptr, nullptr);
    k_conv64<1><<<dim3(8, 8, 8), 256, 0, stream>>>(ee1, ec_w2, ec_b2, out,
                                                   x, ew, alpha);
}

// Round 2
// 344.974 us; speedup vs baseline: 1.4940x; 1.4940x over previous
//
#include <hip/hip_runtime.h>
#include <math.h>

#define Hd 128
#define Wd 128
#define HW 16384      // 128*128
#define EPSc 1e-6f

// ---------------------------------------------------------------------------
// K0: weight transposes into ws. Layouts (all co-contiguous for s_load_dwordx16):
//  ec_w1t/ec_w2t: [ci64][tap9][co64]   (36864 each)
//  ga_w1t:        [ci128][co64]        (8192)
//  ga_w2t:        [ci64][co16]         (1024)
//  cd_w1t:        [ci16][tap9][co16]   (2304)
__global__ void k_prep(const float* __restrict__ ga_w1, const float* __restrict__ ga_w2,
                       const float* __restrict__ cd_w1,
                       const float* __restrict__ ec_w1, const float* __restrict__ ec_w2,
                       float* __restrict__ ga_w1t, float* __restrict__ ga_w2t,
                       float* __restrict__ cd_w1t,
                       float* __restrict__ ec_w1t, float* __restrict__ ec_w2t) {
    int i = blockIdx.x * 256 + threadIdx.x;
    if (i < 36864) {                               // ec_w1t
        int co = i & 63, r = i >> 6, t = r % 9, ci = r / 9;
        ec_w1t[i] = ec_w1[(co * 64 + ci) * 9 + t];
    } else if (i < 73728) {                        // ec_w2t
        int j = i - 36864;
        int co = j & 63, r = j >> 6, t = r % 9, ci = r / 9;
        ec_w2t[j] = ec_w2[(co * 64 + ci) * 9 + t];
    } else if (i < 81920) {                        // ga_w1t [ci128][co64]
        int j = i - 73728;
        int co = j & 63, ci = j >> 6;
        ga_w1t[j] = ga_w1[co * 128 + ci];
    } else if (i < 82944) {                        // ga_w2t [ci64][co16]
        int j = i - 81920;
        int co = j & 15, ci = j >> 4;
        ga_w2t[j] = ga_w2[co * 64 + ci];
    } else if (i < 85248) {                        // cd_w1t [ci16][tap9][co16]
        int j = i - 82944;
        int co = j & 15, r = j >> 4, t = r % 9, ci = r / 9;
        cd_w1t[j] = cd_w1[(co * 16 + ci) * 9 + t];
    }
}

// ---------------------------------------------------------------------------
// K1: depthwise 3x3 sobel -> gx, gy, mag, dir.  grid (8,8,128), block (16,16)
__global__ void k_sobel(const float* __restrict__ x,
                        const float* __restrict__ wgx,
                        const float* __restrict__ wgy,
                        float* __restrict__ gx, float* __restrict__ gy,
                        float* __restrict__ mag, float* __restrict__ dir) {
    int tx = threadIdx.x, ty = threadIdx.y;
    int xw = blockIdx.x * 16 + tx;
    int yh = blockIdx.y * 16 + ty;
    int bc = blockIdx.z;            // b*64 + c
    int c  = bc & 63;
    const float* xp = x + (size_t)bc * HW;
    float wx[9], wy[9];
#pragma unroll
    for (int i = 0; i < 9; i++) { wx[i] = wgx[c * 9 + i]; wy[i] = wgy[c * 9 + i]; }
    float sx = 0.f, sy = 0.f;
#pragma unroll
    for (int dy = -1; dy <= 1; dy++) {
        int yy = yh + dy;
#pragma unroll
        for (int dx = -1; dx <= 1; dx++) {
            int xx = xw + dx;
            float v = (yy >= 0 && yy < Hd && xx >= 0 && xx < Wd) ? xp[yy * Wd + xx] : 0.f;
            int t = (dy + 1) * 3 + (dx + 1);
            sx = fmaf(wx[t], v, sx);
            sy = fmaf(wy[t], v, sy);
        }
    }
    int o = bc * HW + yh * Wd + xw;
    gx[o] = sx;
    gy[o] = sy;
    mag[o] = sqrtf(sx * sx + sy * sy + EPSc);
    dir[o] = atan2f(sy, sx);
}

// ---------------------------------------------------------------------------
// K2: 1x1 conv [64 out][128 in] + relu.  grid (128,4), block 256.
// thread = 1 pixel x 16 co; weights ga_w1t [ci][co] -> s_load_dwordx16 per ci.
__global__ void k_ga1(const float* __restrict__ gx, const float* __restrict__ gy,
                      const float* __restrict__ w1t, const float* __restrict__ b1,
                      float* __restrict__ ga1) {
    int p = blockIdx.x * 256 + threadIdx.x;   // 0..32767
    int cb = blockIdx.y * 16;
    int b = p >> 14;
    int s = p & (HW - 1);
    const float* gxp = gx + (size_t)b * 64 * HW + s;
    const float* gyp = gy + (size_t)b * 64 * HW + s;
    float acc[16];
#pragma unroll
    for (int co = 0; co < 16; co++) acc[co] = b1[cb + co];
    for (int ci = 0; ci < 64; ci++) {
        float v = gxp[ci * HW];
        const float* wp = w1t + ci * 64 + cb;
#pragma unroll
        for (int co = 0; co < 16; co++) acc[co] = fmaf(v, wp[co], acc[co]);
    }
    for (int ci = 0; ci < 64; ci++) {
        float v = gyp[ci * HW];
        const float* wp = w1t + (64 + ci) * 64 + cb;
#pragma unroll
        for (int co = 0; co < 16; co++) acc[co] = fmaf(v, wp[co], acc[co]);
    }
    float* op = ga1 + (size_t)b * 64 * HW + s;
#pragma unroll
    for (int co = 0; co < 16; co++) op[(cb + co) * HW] = fmaxf(acc[co], 0.f);
}

// ---------------------------------------------------------------------------
// K2b: 1x1 conv [16 out][64 in] + relu. grid 128, block 256.
__global__ void k_ga2(const float* __restrict__ ga1, const float* __restrict__ w2t,
                      const float* __restrict__ b2, float* __restrict__ ga2) {
    int p = blockIdx.x * 256 + threadIdx.x;
    int b = p >> 14;
    int s = p & (HW - 1);
    const float* ip = ga1 + (size_t)b * 64 * HW + s;
    float acc[16];
#pragma unroll
    for (int co = 0; co < 16; co++) acc[co] = b2[co];
    for (int ci = 0; ci < 64; ci++) {
        float v = ip[ci * HW];
        const float* wp = w2t + ci * 16;
#pragma unroll
        for (int co = 0; co < 16; co++) acc[co] = fmaf(v, wp[co], acc[co]);
    }
    float* op = ga2 + (size_t)b * 16 * HW + s;
#pragma unroll
    for (int co = 0; co < 16; co++) op[co * HW] = fmaxf(acc[co], 0.f);
}

// ---------------------------------------------------------------------------
// K3: 5x5 windowed weighted circular-variance, fused channel-mean (atomicAdd).
// grid (8,8, B*4=8), block 256 (16x16 tile), 16 channels per block.
__global__ __launch_bounds__(256, 4)
void k_cons(const float* __restrict__ mag, const float* __restrict__ dir,
            float* __restrict__ cm) {
    __shared__ float lm[400], ld[400];
    int tid = threadIdx.x;
    int tx = tid & 15, ty = tid >> 4;
    int x0 = blockIdx.x * 16, y0 = blockIdx.y * 16;
    int b = blockIdx.z >> 2, cb = (blockIdx.z & 3) * 16;
    float acc = 0.f;
    for (int c = 0; c < 16; c++) {
        const float* mp = mag + (size_t)(b * 64 + cb + c) * HW;
        const float* dp = dir + (size_t)(b * 64 + cb + c) * HW;
        __syncthreads();
        for (int i = tid; i < 400; i += 256) {
            int yy = i / 20, xx = i - yy * 20;
            int gy = y0 - 2 + yy, gx = x0 - 2 + xx;
            bool ok = (gy >= 0 && gy < Hd && gx >= 0 && gx < Wd);
            lm[i] = ok ? mp[gy * Wd + gx] : 0.f;
            ld[i] = ok ? dp[gy * Wd + gx] : 0.f;
        }
        __syncthreads();
        float mv[25], dv[25];
        float sm = 0.f, sdm = 0.f;
#pragma unroll
        for (int r = 0; r < 5; r++) {
#pragma unroll
            for (int cx = 0; cx < 5; cx++) {
                int idx = (ty + r) * 20 + tx + cx;
                float m = lm[idx], d = ld[idx];
                mv[r * 5 + cx] = m;
                dv[r * 5 + cx] = d;
                sm += m;
                sdm = fmaf(d, m, sdm);
            }
        }
        float wmean = sdm / (sm + EPSc);
        float sv = 0.f;
#pragma unroll
        for (int t = 0; t < 25; t++) { float dd = dv[t] - wmean; sv = fmaf(dd * dd, mv[t], sv); }
        float wstd = sqrtf(sv / (sm + EPSc));
        acc += 1.f - tanhf(wstd);
    }
    atomicAdd(&cm[b * HW + (y0 + ty) * Wd + x0 + tx], acc * (1.f / 64.f));
}

// ---------------------------------------------------------------------------
// K5+K6 fused: 3x3 conv [16][16] + relu + 1x1 [1][16] + sigmoid, * cm -> ew
// grid (8,8,2), block 256.
__global__ __launch_bounds__(256, 4)
void k_cd1ew(const float* __restrict__ ga2, const float* __restrict__ w1t,
             const float* __restrict__ b1, const float* __restrict__ w2,
             const float* __restrict__ b2, const float* __restrict__ cm,
             float* __restrict__ ew) {
    __shared__ float lds[16][324];
    int tid = threadIdx.x;
    int tx = tid & 15, ty = tid >> 4;
    int x0 = blockIdx.x * 16, y0 = blockIdx.y * 16;
    int b = blockIdx.z;
    const float* ip = ga2 + (size_t)b * 16 * HW;
    float acc[16];
#pragma unroll
    for (int co = 0; co < 16; co++) acc[co] = b1[co];
#pragma unroll
    for (int ci = 0; ci < 16; ci++) {
        const float* sp = ip + ci * HW;
        for (int i = tid; i < 324; i += 256) {
            int yy = i / 18, xx = i - yy * 18;
            int gy = y0 - 1 + yy, gx = x0 - 1 + xx;
            lds[ci][i] = (gy >= 0 && gy < Hd && gx >= 0 && gx < Wd) ? sp[gy * Wd + gx] : 0.f;
        }
    }
    __syncthreads();
    for (int ci = 0; ci < 16; ci++) {
        const float* wp = w1t + ci * 9 * 16;
        float pv[9];
#pragma unroll
        for (int r = 0; r < 3; r++)
#pragma unroll
            for (int cx = 0; cx < 3; cx++)
                pv[r * 3 + cx] = lds[ci][(ty + r) * 18 + tx + cx];
#pragma unroll
        for (int t = 0; t < 9; t++)
#pragma unroll
            for (int co = 0; co < 16; co++)
                acc[co] = fmaf(pv[t], wp[t * 16 + co], acc[co]);
    }
    float e = b2[0];
#pragma unroll
    for (int co = 0; co < 16; co++) e = fmaf(fmaxf(acc[co], 0.f), w2[co], e);
    float sig = 1.f / (1.f + expf(-e));
    int sp = (y0 + ty) * Wd + x0 + tx;
    ew[b * HW + sp] = sig * cm[b * HW + sp];
}

// ---------------------------------------------------------------------------
// K7/K8: 3x3 conv [64][64], LDS-tiled, transposed weights [ci][tap][co].
// grid (8,8,8), block 256. FINAL=0: relu; FINAL=1: out = x + alpha*ew*conv.
template <int FINAL>
__global__ __launch_bounds__(256, 4)
void k_conv64(const float* __restrict__ in, const float* __restrict__ wt,
              const float* __restrict__ bias, float* __restrict__ out,
              const float* __restrict__ x, const float* __restrict__ ew,
              const float* __restrict__ alpha_p) {
    __shared__ float lds[16][324];   // 20.7 KB
    int tid = threadIdx.x;
    int tx = tid & 15, ty = tid >> 4;
    int x0 = blockIdx.x * 16, y0 = blockIdx.y * 16;
    int b = blockIdx.z >> 2;
    int co_base = (blockIdx.z & 3) * 16;
    const float* ip = in + (size_t)b * 64 * HW;
    float acc[16];
#pragma unroll
    for (int co = 0; co < 16; co++) acc[co] = bias[co_base + co];

    for (int cc = 0; cc < 4; cc++) {     // 4 chunks of 16 input channels
        __syncthreads();
#pragma unroll
        for (int ci = 0; ci < 16; ci++) {
            const float* sp = ip + (cc * 16 + ci) * HW;
            for (int i = tid; i < 324; i += 256) {
                int yy = i / 18, xx = i - yy * 18;
                int gy = y0 - 1 + yy, gx = x0 - 1 + xx;
                lds[ci][i] = (gy >= 0 && gy < Hd && gx >= 0 && gx < Wd)
                                 ? sp[gy * Wd + gx] : 0.f;
            }
        }
        __syncthreads();
        for (int ci = 0; ci < 16; ci++) {
            const float* wp = wt + (size_t)((cc * 16 + ci) * 9) * 64 + co_base;
            float pv[9];
#pragma unroll
            for (int r = 0; r < 3; r++)
#pragma unroll
                for (int cx = 0; cx < 3; cx++)
                    pv[r * 3 + cx] = lds[ci][(ty + r) * 18 + tx + cx];
#pragma unroll
            for (int t = 0; t < 9; t++)
#pragma unroll
                for (int co = 0; co < 16; co++)
                    acc[co] = fmaf(pv[t], wp[t * 64 + co], acc[co]);
        }
    }
    int sp = (y0 + ty) * Wd + (x0 + tx);
    if (FINAL) {
        float ae = alpha_p[0] * ew[b * HW + sp];
#pragma unroll
        for (int co = 0; co < 16; co++) {
            size_t o = (size_t)(b * 64 + co_base + co) * HW + sp;
            out[o] = fmaf(ae, acc[co], x[o]);
        }
    } else {
#pragma unroll
        for (int co = 0; co < 16; co++)
            out[(size_t)(b * 64 + co_base + co) * HW + sp] = fmaxf(acc[co], 0.f);
    }
}

// ---------------------------------------------------------------------------
extern "C" void kernel_launch(void* const* d_in, const int* in_sizes, int n_in,
                              void* d_out, int out_size, void* d_ws, size_t ws_size,
                              hipStream_t stream) {
    const float* x     = (const float*)d_in[0];
    const float* wgx   = (const float*)d_in[1];
    const float* wgy   = (const float*)d_in[2];
    const float* ga_w1 = (const float*)d_in[3];
    const float* ga_b1 = (const float*)d_in[4];
    const float* ga_w2 = (const float*)d_in[5];
    const float* ga_b2 = (const float*)d_in[6];
    const float* cd_w1 = (const float*)d_in[7];
    const float* cd_b1 = (const float*)d_in[8];
    const float* cd_w2 = (const float*)d_in[9];
    const float* cd_b2 = (const float*)d_in[10];
    const float* ec_w1 = (const float*)d_in[11];
    const float* ec_b1 = (const float*)d_in[12];
    const float* ec_w2 = (const float*)d_in[13];
    const float* ec_b2 = (const float*)d_in[14];
    const float* alpha = (const float*)d_in[15];
    float* out = (float*)d_out;
    float* ws  = (float*)d_ws;

    const size_t N = 2 * 64 * HW;   // 2,097,152 floats

    // buffer plan (aliased by liveness):
    float* gx    = ws + 0 * N;       // dead after k_ga1
    float* gy    = ws + 1 * N;       // dead after k_ga1
    float* mag   = ws + 2 * N;       // dead after k_cons -> reused as ee1
    float* dirb  = ws + 3 * N;       // dead after k_cons
    float* ga1   = ws + 4 * N;       // dead after k_ga2
    float* ga2   = ws + 5 * N;                   // 524288 floats
    float* cm    = ga2 + 2 * 16 * HW;            // 32768
    float* ew    = cm + 2 * HW;                  // 32768
    float* wts   = ew + 2 * HW;
    float* ec_w1t = wts;                         // 36864
    float* ec_w2t = ec_w1t + 36864;              // 36864
    float* ga_w1t = ec_w2t + 36864;              // 8192
    float* ga_w2t = ga_w1t + 8192;               // 1024
    float* cd_w1t = ga_w2t + 1024;               // 2304
    float* ee1   = mag;

    k_prep<<<334, 256, 0, stream>>>(ga_w1, ga_w2, cd_w1, ec_w1, ec_w2,
                                    ga_w1t, ga_w2t, cd_w1t, ec_w1t, ec_w2t);
    hipMemsetAsync(cm, 0, 2 * HW * sizeof(float), stream);

    dim3 b16(16, 16);
    k_sobel<<<dim3(8, 8, 128), b16, 0, stream>>>(x, wgx, wgy, gx, gy, mag, dirb);
    k_ga1<<<dim3(128, 4), 256, 0, stream>>>(gx, gy, ga_w1t, ga_b1, ga1);
    k_ga2<<<128, 256, 0, stream>>>(ga1, ga_w2t, ga_b2, ga2);
    k_cons<<<dim3(8, 8, 8), 256, 0, stream>>>(mag, dirb, cm);
    k_cd1ew<<<dim3(8, 8, 2), 256, 0, stream>>>(ga2, cd_w1t, cd_b1, cd_w2, cd_b2, cm, ew);
    k_conv64<0><<<dim3(8, 8, 8), 256, 0, stream>>>(x, ec_w1t, ec_b1, ee1,
                                                   nullptr, nullptr, nullptr);
    k_conv64<1><<<dim3(8, 8, 8), 256, 0, stream>>>(ee1, ec_w2t, ec_b2, out,
                                                   x, ew, alpha);
}

// Round 3
// 203.897 us; speedup vs baseline: 2.5278x; 1.6919x over previous
//
#include <hip/hip_runtime.h>
#include <math.h>

#define Hd 128
#define Wd 128
#define HW 16384      // 128*128
#define EPSc 1e-6f

typedef __attribute__((ext_vector_type(8))) short s8v;    // 8 bf16 (4 VGPRs)
typedef __attribute__((ext_vector_type(4))) float f4v;    // 4 fp32 acc

__device__ __forceinline__ unsigned short f2bf(float f) {
    unsigned int u = __float_as_uint(f);
    unsigned int r = (u + 0x7FFFu + ((u >> 16) & 1u)) >> 16;   // RNE
    return (unsigned short)r;
}

// ---------------------------------------------------------------------------
// K0: weight prep.
//  w1h/w2h:  [tap9][co64][ci64] bf16   (36864 each)   for MFMA convs
//  ga_w1t:   [ci128][co64] fp32        (8192)
//  ga_w2t:   [ci64][co16] fp32         (1024)
//  cd_w1t:   [ci16][tap9][co16] fp32   (2304)
__global__ void k_prep(const float* __restrict__ ga_w1, const float* __restrict__ ga_w2,
                       const float* __restrict__ cd_w1,
                       const float* __restrict__ ec_w1, const float* __restrict__ ec_w2,
                       float* __restrict__ ga_w1t, float* __restrict__ ga_w2t,
                       float* __restrict__ cd_w1t,
                       unsigned short* __restrict__ w1h, unsigned short* __restrict__ w2h) {
    int i = blockIdx.x * 256 + threadIdx.x;
    if (i < 36864) {                               // w1h [t][co][ci]
        int t = i >> 12, co = (i >> 6) & 63, ci = i & 63;
        w1h[i] = f2bf(ec_w1[(co * 64 + ci) * 9 + t]);
    } else if (i < 73728) {                        // w2h
        int j = i - 36864;
        int t = j >> 12, co = (j >> 6) & 63, ci = j & 63;
        w2h[j] = f2bf(ec_w2[(co * 64 + ci) * 9 + t]);
    } else if (i < 81920) {                        // ga_w1t [ci128][co64]
        int j = i - 73728;
        int co = j & 63, ci = j >> 6;
        ga_w1t[j] = ga_w1[co * 128 + ci];
    } else if (i < 82944) {                        // ga_w2t [ci64][co16]
        int j = i - 81920;
        int co = j & 15, ci = j >> 4;
        ga_w2t[j] = ga_w2[co * 64 + ci];
    } else if (i < 85248) {                        // cd_w1t [ci16][tap9][co16]
        int j = i - 82944;
        int co = j & 15, r = j >> 4, t = r % 9, ci = r / 9;
        cd_w1t[j] = cd_w1[(co * 16 + ci) * 9 + t];
    }
}

// ---------------------------------------------------------------------------
// K_xh: x NCHW fp32 -> xh NHWC bf16 [b][y][x][64]. grid 128 x 256.
__global__ void k_xh(const float* __restrict__ x, unsigned short* __restrict__ xh) {
    int p = blockIdx.x * 256 + threadIdx.x;   // 0..32767
    int b = p >> 14, s = p & (HW - 1);
    const float* xp = x + (size_t)b * 64 * HW + s;
    alignas(16) unsigned short buf[64];
#pragma unroll
    for (int c = 0; c < 64; c++) buf[c] = f2bf(xp[c * HW]);
    uint4* dst = (uint4*)(xh + (size_t)p * 64);
    const uint4* src = (const uint4*)buf;
#pragma unroll
    for (int i = 0; i < 8; i++) dst[i] = src[i];
}

// ---------------------------------------------------------------------------
// K1: depthwise 3x3 sobel -> gx, gy, mag, dir.  grid (8,8,128), block (16,16)
__global__ void k_sobel(const float* __restrict__ x,
                        const float* __restrict__ wgx,
                        const float* __restrict__ wgy,
                        float* __restrict__ gx, float* __restrict__ gy,
                        float* __restrict__ mag, float* __restrict__ dir) {
    int tx = threadIdx.x, ty = threadIdx.y;
    int xw = blockIdx.x * 16 + tx;
    int yh = blockIdx.y * 16 + ty;
    int bc = blockIdx.z;            // b*64 + c
    int c  = bc & 63;
    const float* xp = x + (size_t)bc * HW;
    float wx[9], wy[9];
#pragma unroll
    for (int i = 0; i < 9; i++) { wx[i] = wgx[c * 9 + i]; wy[i] = wgy[c * 9 + i]; }
    float sx = 0.f, sy = 0.f;
#pragma unroll
    for (int dy = -1; dy <= 1; dy++) {
        int yy = yh + dy;
#pragma unroll
        for (int dx = -1; dx <= 1; dx++) {
            int xx = xw + dx;
            float v = (yy >= 0 && yy < Hd && xx >= 0 && xx < Wd) ? xp[yy * Wd + xx] : 0.f;
            int t = (dy + 1) * 3 + (dx + 1);
            sx = fmaf(wx[t], v, sx);
            sy = fmaf(wy[t], v, sy);
        }
    }
    int o = bc * HW + yh * Wd + xw;
    gx[o] = sx;
    gy[o] = sy;
    mag[o] = sqrtf(sx * sx + sy * sy + EPSc);
    dir[o] = atan2f(sy, sx);
}

// ---------------------------------------------------------------------------
// K2: 1x1 conv [64 out][128 in] + relu.  grid (128,4), block 256.
__global__ void k_ga1(const float* __restrict__ gx, const float* __restrict__ gy,
                      const float* __restrict__ w1t, const float* __restrict__ b1,
                      float* __restrict__ ga1) {
    int p = blockIdx.x * 256 + threadIdx.x;   // 0..32767
    int cb = blockIdx.y * 16;
    int b = p >> 14;
    int s = p & (HW - 1);
    const float* gxp = gx + (size_t)b * 64 * HW + s;
    const float* gyp = gy + (size_t)b * 64 * HW + s;
    float acc[16];
#pragma unroll
    for (int co = 0; co < 16; co++) acc[co] = b1[cb + co];
    for (int ci = 0; ci < 64; ci++) {
        float v = gxp[ci * HW];
        const float* wp = w1t + ci * 64 + cb;
#pragma unroll
        for (int co = 0; co < 16; co++) acc[co] = fmaf(v, wp[co], acc[co]);
    }
    for (int ci = 0; ci < 64; ci++) {
        float v = gyp[ci * HW];
        const float* wp = w1t + (64 + ci) * 64 + cb;
#pragma unroll
        for (int co = 0; co < 16; co++) acc[co] = fmaf(v, wp[co], acc[co]);
    }
    float* op = ga1 + (size_t)b * 64 * HW + s;
#pragma unroll
    for (int co = 0; co < 16; co++) op[(cb + co) * HW] = fmaxf(acc[co], 0.f);
}

// ---------------------------------------------------------------------------
// K2b: 1x1 conv [16 out][64 in] + relu. grid 128, block 256.
__global__ void k_ga2(const float* __restrict__ ga1, const float* __restrict__ w2t,
                      const float* __restrict__ b2, float* __restrict__ ga2) {
    int p = blockIdx.x * 256 + threadIdx.x;
    int b = p >> 14;
    int s = p & (HW - 1);
    const float* ip = ga1 + (size_t)b * 64 * HW + s;
    float acc[16];
#pragma unroll
    for (int co = 0; co < 16; co++) acc[co] = b2[co];
    for (int ci = 0; ci < 64; ci++) {
        float v = ip[ci * HW];
        const float* wp = w2t + ci * 16;
#pragma unroll
        for (int co = 0; co < 16; co++) acc[co] = fmaf(v, wp[co], acc[co]);
    }
    float* op = ga2 + (size_t)b * 16 * HW + s;
#pragma unroll
    for (int co = 0; co < 16; co++) op[co * HW] = fmaxf(acc[co], 0.f);
}

// ---------------------------------------------------------------------------
// K3: 5x5 windowed weighted circular-variance, fused channel-mean (atomicAdd).
// grid (8,8,8), block 256, 16 channels per block.
__global__ __launch_bounds__(256, 4)
void k_cons(const float* __restrict__ mag, const float* __restrict__ dir,
            float* __restrict__ cm) {
    __shared__ float lm[400], ld[400];
    int tid = threadIdx.x;
    int tx = tid & 15, ty = tid >> 4;
    int x0 = blockIdx.x * 16, y0 = blockIdx.y * 16;
    int b = blockIdx.z >> 2, cb = (blockIdx.z & 3) * 16;
    float acc = 0.f;
    for (int c = 0; c < 16; c++) {
        const float* mp = mag + (size_t)(b * 64 + cb + c) * HW;
        const float* dp = dir + (size_t)(b * 64 + cb + c) * HW;
        __syncthreads();
        for (int i = tid; i < 400; i += 256) {
            int yy = i / 20, xx = i - yy * 20;
            int gy = y0 - 2 + yy, gx = x0 - 2 + xx;
            bool ok = (gy >= 0 && gy < Hd && gx >= 0 && gx < Wd);
            lm[i] = ok ? mp[gy * Wd + gx] : 0.f;
            ld[i] = ok ? dp[gy * Wd + gx] : 0.f;
        }
        __syncthreads();
        float mv[25], dv[25];
        float sm = 0.f, sdm = 0.f;
#pragma unroll
        for (int r = 0; r < 5; r++) {
#pragma unroll
            for (int cx = 0; cx < 5; cx++) {
                int idx = (ty + r) * 20 + tx + cx;
                float m = lm[idx], d = ld[idx];
                mv[r * 5 + cx] = m;
                dv[r * 5 + cx] = d;
                sm += m;
                sdm = fmaf(d, m, sdm);
            }
        }
        float wmean = sdm / (sm + EPSc);
        float sv = 0.f;
#pragma unroll
        for (int t = 0; t < 25; t++) { float dd = dv[t] - wmean; sv = fmaf(dd * dd, mv[t], sv); }
        float wstd = sqrtf(sv / (sm + EPSc));
        acc += 1.f - tanhf(wstd);
    }
    atomicAdd(&cm[b * HW + (y0 + ty) * Wd + x0 + tx], acc * (1.f / 64.f));
}

// ---------------------------------------------------------------------------
// K5+K6 fused: 3x3 conv [16][16] + relu + 1x1 [1][16] + sigmoid, * cm -> ew
// grid (8,8,2), block 256.
__global__ __launch_bounds__(256, 4)
void k_cd1ew(const float* __restrict__ ga2, const float* __restrict__ w1t,
             const float* __restrict__ b1, const float* __restrict__ w2,
             const float* __restrict__ b2, const float* __restrict__ cm,
             float* __restrict__ ew) {
    __shared__ float lds[16][324];
    int tid = threadIdx.x;
    int tx = tid & 15, ty = tid >> 4;
    int x0 = blockIdx.x * 16, y0 = blockIdx.y * 16;
    int b = blockIdx.z;
    const float* ip = ga2 + (size_t)b * 16 * HW;
    float acc[16];
#pragma unroll
    for (int co = 0; co < 16; co++) acc[co] = b1[co];
#pragma unroll
    for (int ci = 0; ci < 16; ci++) {
        const float* sp = ip + ci * HW;
        for (int i = tid; i < 324; i += 256) {
            int yy = i / 18, xx = i - yy * 18;
            int gy = y0 - 1 + yy, gx = x0 - 1 + xx;
            lds[ci][i] = (gy >= 0 && gy < Hd && gx >= 0 && gx < Wd) ? sp[gy * Wd + gx] : 0.f;
        }
    }
    __syncthreads();
    for (int ci = 0; ci < 16; ci++) {
        const float* wp = w1t + ci * 9 * 16;
        float pv[9];
#pragma unroll
        for (int r = 0; r < 3; r++)
#pragma unroll
            for (int cx = 0; cx < 3; cx++)
                pv[r * 3 + cx] = lds[ci][(ty + r) * 18 + tx + cx];
#pragma unroll
        for (int t = 0; t < 9; t++)
#pragma unroll
            for (int co = 0; co < 16; co++)
                acc[co] = fmaf(pv[t], wp[t * 16 + co], acc[co]);
    }
    float e = b2[0];
#pragma unroll
    for (int co = 0; co < 16; co++) e = fmaf(fmaxf(acc[co], 0.f), w2[co], e);
    float sig = 1.f / (1.f + expf(-e));
    int sp = (y0 + ty) * Wd + x0 + tx;
    ew[b * HW + sp] = sig * cm[b * HW + sp];
}

// ---------------------------------------------------------------------------
// K7/K8: 3x3 conv [64][64] via bf16 MFMA implicit GEMM, tap-split.
// Input NHWC bf16 [b][y][x][64]; weights [tap][co][ci] bf16.
// Block: 8x8 output tile x 64 co, 4 waves (wave w -> co 16w..16w+15).
// LDS: 10x10x64 bf16 halo tile, ci-octet XOR-swizzled vs (rowlin&7).
// FINAL=0: relu -> bf16 NHWC out. FINAL=1: out = x + alpha*ew*acc (fp32 NCHW).
template <int FINAL>
__global__ __launch_bounds__(256, 2)
void k_conv64m(const unsigned short* __restrict__ inh,
               const unsigned short* __restrict__ wh,
               const float* __restrict__ bias,
               unsigned short* __restrict__ outh,
               float* __restrict__ outf,
               const float* __restrict__ x,
               const float* __restrict__ ew,
               const float* __restrict__ alpha_p) {
    __shared__ unsigned short tile[100 * 64];   // 12.8 KB
    int tid = threadIdx.x;
    int x0 = blockIdx.x * 8, y0 = blockIdx.y * 8;
    int b = blockIdx.z;
    const size_t ibase = (size_t)b * HW * 64;

    // stage 10x10x64 bf16 halo tile (coalesced 16B loads, swizzled LDS writes)
    for (int i = tid; i < 800; i += 256) {
        int py = i / 80;
        int r = i - py * 80;
        int px = r >> 3, cg = r & 7;
        int gy = y0 - 1 + py, gx = x0 - 1 + px;
        uint4 v = {0u, 0u, 0u, 0u};
        if (gy >= 0 && gy < Hd && gx >= 0 && gx < Wd)
            v = *(const uint4*)(inh + ibase + (size_t)(gy * Wd + gx) * 64 + cg * 8);
        int rowlin = py * 10 + px;
        int scg = cg ^ (rowlin & 7);
        *(uint4*)(tile + rowlin * 64 + scg * 8) = v;
    }

    int lane = tid & 63;
    int wv = tid >> 6;
    int l15 = lane & 15, lq = lane >> 4;
    int co_base = wv * 16;

    // preload 18 A-fragments (held in VGPRs for whole kernel)
    s8v af[9][2];
#pragma unroll
    for (int t = 0; t < 9; t++)
#pragma unroll
        for (int h = 0; h < 2; h++)
            af[t][h] = *(const s8v*)(wh + ((t * 64 + co_base + l15) * 64 + h * 32 + lq * 8));

    f4v bv = *(const f4v*)(bias + co_base + lq * 4);
    f4v acc[4];
#pragma unroll
    for (int n = 0; n < 4; n++) acc[n] = bv;

    __syncthreads();

#pragma unroll
    for (int n = 0; n < 4; n++) {
        int px = n * 16 + l15;
        int pyy = px >> 3, pxx = px & 7;
#pragma unroll
        for (int dy = 0; dy < 3; dy++) {
#pragma unroll
            for (int dx = 0; dx < 3; dx++) {
                int rowlin = (pyy + dy) * 10 + (pxx + dx);
                int sw = rowlin & 7;
                const unsigned short* tp = tile + rowlin * 64;
                s8v b0 = *(const s8v*)(tp + (lq ^ sw) * 8);
                s8v b1 = *(const s8v*)(tp + ((4 + lq) ^ sw) * 8);
                int t = dy * 3 + dx;
                acc[n] = __builtin_amdgcn_mfma_f32_16x16x32_bf16(af[t][0], b0, acc[n], 0, 0, 0);
                acc[n] = __builtin_amdgcn_mfma_f32_16x16x32_bf16(af[t][1], b1, acc[n], 0, 0, 0);
            }
        }
    }

#pragma unroll
    for (int n = 0; n < 4; n++) {
        int px = n * 16 + l15;
        int gyo = y0 + (px >> 3), gxo = x0 + (px & 7);
        int sp = gyo * Wd + gxo;
        if (FINAL) {
            float ae = alpha_p[0] * ew[b * HW + sp];
#pragma unroll
            for (int r = 0; r < 4; r++) {
                size_t o = (size_t)(b * 64 + co_base + lq * 4 + r) * HW + sp;
                outf[o] = fmaf(ae, acc[n][r], x[o]);
            }
        } else {
            alignas(8) unsigned short pk[4];
#pragma unroll
            for (int r = 0; r < 4; r++) pk[r] = f2bf(fmaxf(acc[n][r], 0.f));
            *(uint2*)(outh + ibase + (size_t)sp * 64 + co_base + lq * 4) = *(const uint2*)pk;
        }
    }
}

// ---------------------------------------------------------------------------
extern "C" void kernel_launch(void* const* d_in, const int* in_sizes, int n_in,
                              void* d_out, int out_size, void* d_ws, size_t ws_size,
                              hipStream_t stream) {
    const float* x     = (const float*)d_in[0];
    const float* wgx   = (const float*)d_in[1];
    const float* wgy   = (const float*)d_in[2];
    const float* ga_w1 = (const float*)d_in[3];
    const float* ga_b1 = (const float*)d_in[4];
    const float* ga_w2 = (const float*)d_in[5];
    const float* ga_b2 = (const float*)d_in[6];
    const float* cd_w1 = (const float*)d_in[7];
    const float* cd_b1 = (const float*)d_in[8];
    const float* cd_w2 = (const float*)d_in[9];
    const float* cd_b2 = (const float*)d_in[10];
    const float* ec_w1 = (const float*)d_in[11];
    const float* ec_b1 = (const float*)d_in[12];
    const float* ec_w2 = (const float*)d_in[13];
    const float* ec_b2 = (const float*)d_in[14];
    const float* alpha = (const float*)d_in[15];
    float* out = (float*)d_out;
    float* ws  = (float*)d_ws;

    const size_t N = 2 * 64 * HW;   // 2,097,152 floats

    // buffer plan (aliased by liveness):
    float* gx    = ws + 0 * N;        // dead after k_ga1
    float* gy    = ws + 1 * N;        // dead after k_ga1
    float* mag   = ws + 2 * N;        // dead after k_cons -> reused as xh (bf16)
    float* dirb  = ws + 3 * N;        // dead after k_cons -> reused as ee1h (bf16)
    float* ga1   = ws + 4 * N;        // dead after k_ga2
    float* ga2   = ws + 5 * N;                    // 524288 floats
    float* cm    = ga2 + 2 * 16 * HW;             // 32768
    float* ew    = cm + 2 * HW;                   // 32768
    float* ga_w1t = ew + 2 * HW;                  // 8192
    float* ga_w2t = ga_w1t + 8192;                // 1024
    float* cd_w1t = ga_w2t + 1024;                // 2304
    unsigned short* w1h = (unsigned short*)(cd_w1t + 2304);  // 36864 shorts
    unsigned short* w2h = w1h + 36864;                       // 36864 shorts
    unsigned short* xh   = (unsigned short*)mag;             // 2M shorts (fits in N floats)
    unsigned short* ee1h = (unsigned short*)dirb;            // 2M shorts

    k_prep<<<333, 256, 0, stream>>>(ga_w1, ga_w2, cd_w1, ec_w1, ec_w2,
                                    ga_w1t, ga_w2t, cd_w1t, w1h, w2h);
    hipMemsetAsync(cm, 0, 2 * HW * sizeof(float), stream);

    dim3 b16(16, 16);
    k_sobel<<<dim3(8, 8, 128), b16, 0, stream>>>(x, wgx, wgy, gx, gy, mag, dirb);
    k_ga1<<<dim3(128, 4), 256, 0, stream>>>(gx, gy, ga_w1t, ga_b1, ga1);
    k_ga2<<<128, 256, 0, stream>>>(ga1, ga_w2t, ga_b2, ga2);
    k_cons<<<dim3(8, 8, 8), 256, 0, stream>>>(mag, dirb, cm);
    k_cd1ew<<<dim3(8, 8, 2), 256, 0, stream>>>(ga2, cd_w1t, cd_b1, cd_w2, cd_b2, cm, ew);
    k_xh<<<128, 256, 0, stream>>>(x, xh);        // mag/dirb dead from here on
    k_conv64m<0><<<dim3(16, 16, 2), 256, 0, stream>>>(xh, w1h, ec_b1, ee1h,
                                                      nullptr, nullptr, nullptr, nullptr);
    k_conv64m<1><<<dim3(16, 16, 2), 256, 0, stream>>>(ee1h, w2h, ec_b2, nullptr,
                                                      out, x, ew, alpha);
}